// Round 1
// baseline (344.250 us; speedup 1.0000x reference)
//
#include <hip/hip_runtime.h>

typedef __attribute__((ext_vector_type(8))) short short8;
typedef __attribute__((ext_vector_type(4))) short short4_t;
typedef __attribute__((ext_vector_type(4))) float f32x4;
typedef __attribute__((ext_vector_type(4))) unsigned short u16x4;

__device__ __forceinline__ unsigned short f2b(float f) {
  unsigned int u = __float_as_uint(f);
  u += 0x7fffu + ((u >> 16) & 1u);   // RNE
  return (unsigned short)(u >> 16);
}
__device__ __forceinline__ float b2f(unsigned short s) {
  return __uint_as_float(((unsigned int)s) << 16);
}
__device__ __forceinline__ void glds16(const void* g, void* l) {
  __builtin_amdgcn_global_load_lds(
      (const __attribute__((address_space(1))) unsigned int*)g,
      (__attribute__((address_space(3))) unsigned int*)l, 16, 0, 0);
}

// ---------------------------------------------------------------- casts
__global__ __launch_bounds__(256) void cast_f32_bf16(const float* __restrict__ src,
                                                     unsigned short* __restrict__ dst,
                                                     int n4) {
  int i = blockIdx.x * 256 + threadIdx.x;
  if (i >= n4) return;
  f32x4 v = *(const f32x4*)(src + (size_t)i * 4);
  u16x4 o;
  o[0] = f2b(v[0]); o[1] = f2b(v[1]); o[2] = f2b(v[2]); o[3] = f2b(v[3]);
  *(u16x4*)(dst + (size_t)i * 4) = o;
}

// ------------------------------------------------- GEMM C = A * B^T (m97 structure)
// A: M x K bf16 row-major, B: N x K bf16 row-major; 128x128 tile, BK=32,
// 256 thr = 4 waves in 2x2, each wave 64x64 via 4x4 of mfma 16x16x32.
template <bool BF16_OUT>
__global__ __launch_bounds__(256) void gemm_bt(const unsigned short* __restrict__ A,
                                               const unsigned short* __restrict__ B,
                                               void* __restrict__ Cout,
                                               int M, int N, int K) {
  __shared__ unsigned short As[128 * 32];
  __shared__ unsigned short Bs[128 * 32];
  const int tid = threadIdx.x;
  const int w = tid >> 6, lane = tid & 63;
  const int quad = lane >> 4, l15 = lane & 15;
  const int m0 = blockIdx.x * 128, n0 = blockIdx.y * 128;
  const int mbase = (w >> 1) * 64, nbase = (w & 1) * 64;
  const f32x4 fzero = {0.f, 0.f, 0.f, 0.f};

  f32x4 acc[4][4];
#pragma unroll
  for (int i = 0; i < 4; i++)
#pragma unroll
    for (int j = 0; j < 4; j++) acc[i][j] = fzero;

  // staging: wave w writes bytes [w*1024 + lane*16] of each 64-row segment
  const int srow = w * 16 + (lane >> 2);
  const int scol = (lane & 3) * 8;
  const unsigned short* Ag0 = A + (size_t)(m0 + srow) * K + scol;
  const unsigned short* Ag1 = Ag0 + (size_t)64 * K;
  const unsigned short* Bg0 = B + (size_t)(n0 + srow) * K + scol;
  const unsigned short* Bg1 = Bg0 + (size_t)64 * K;

  for (int k0 = 0; k0 < K; k0 += 32) {
    __syncthreads();
    glds16(Ag0 + k0, &As[w * 512]);
    glds16(Ag1 + k0, &As[2048 + w * 512]);
    glds16(Bg0 + k0, &Bs[w * 512]);
    glds16(Bg1 + k0, &Bs[2048 + w * 512]);
    __syncthreads();
    short8 af[4], bf[4];
#pragma unroll
    for (int mi = 0; mi < 4; mi++)
      af[mi] = *(const short8*)&As[(mbase + mi * 16 + l15) * 32 + quad * 8];
#pragma unroll
    for (int ni = 0; ni < 4; ni++)
      bf[ni] = *(const short8*)&Bs[(nbase + ni * 16 + l15) * 32 + quad * 8];
#pragma unroll
    for (int mi = 0; mi < 4; mi++)
#pragma unroll
      for (int ni = 0; ni < 4; ni++)
        acc[mi][ni] = __builtin_amdgcn_mfma_f32_16x16x32_bf16(af[mi], bf[ni], acc[mi][ni], 0, 0, 0);
  }

#pragma unroll
  for (int mi = 0; mi < 4; mi++)
#pragma unroll
    for (int ni = 0; ni < 4; ni++) {
      const int row = m0 + mbase + mi * 16 + quad * 4;
      const int col = n0 + nbase + ni * 16 + l15;
#pragma unroll
      for (int r = 0; r < 4; r++) {
        if (BF16_OUT)
          ((unsigned short*)Cout)[(size_t)(row + r) * N + col] = f2b(acc[mi][ni][r]);
        else
          ((float*)Cout)[(size_t)(row + r) * N + col] = acc[mi][ni][r];
      }
    }
}

// ---------------------------------------------------------------- RoPE (q + k)
// qkv: (T, 3072) bf16 = [q 16*128 | k 4*128 | v 4*128]; writes q (T,16,128), k (T,4,128)
__global__ __launch_bounds__(256) void rope_kernel(const unsigned short* __restrict__ qkv,
                                                   unsigned short* __restrict__ qo,
                                                   unsigned short* __restrict__ ko) {
  int idx = blockIdx.x * 256 + threadIdx.x;   // T*20*64 = 5,242,880 threads
  int t = idx / 1280;
  int rem = idx - t * 1280;
  int h = rem >> 6, i = rem & 63;
  const unsigned short* base = qkv + (size_t)t * 3072;
  unsigned short* dst;
  float x1, x2;
  if (h < 16) {
    x1 = b2f(base[h * 128 + i]);
    x2 = b2f(base[h * 128 + 64 + i]);
    dst = qo + (size_t)t * 2048 + h * 128;
  } else {
    int hk = h - 16;
    x1 = b2f(base[2048 + hk * 128 + i]);
    x2 = b2f(base[2048 + hk * 128 + 64 + i]);
    dst = ko + (size_t)t * 512 + hk * 128;
  }
  const float c2 = 0.20762050593045889f;      // log2(10000)/64
  float inv = exp2f(-(float)i * c2);          // HW exp2: ~1ulp, matches fp32 ref closely
  float ang = (float)t * inv;
  float sn, cs;
  sincosf(ang, &sn, &cs);                     // precise: args up to ~4095 rad
  dst[i]      = f2b(x1 * cs - x2 * sn);
  dst[64 + i] = f2b(x1 * sn + x2 * cs);
}

// ------------------------------------------------------------ windowed GQA attention
// Block: 256 thr = 4 waves = the 4 q-heads of one kv group; 16 query rows per block.
// S^T = K*Q^T (C-layout: row=key=quad*4+r, col=query=lane&15) -> softmax needs only
// 2 shuffles; P^T in C-layout IS the B-operand layout of mfma 16x16x16, so
// O^T += V^T * P^T needs no cross-lane transform.
__global__ __launch_bounds__(256) void attn_fwd(const unsigned short* __restrict__ qp,
                                                const unsigned short* __restrict__ kp,
                                                const unsigned short* __restrict__ vp, // qkv+2560, stride 3072
                                                unsigned short* __restrict__ op) {
  __shared__ unsigned short Ks[16 * 128];   // K chunk row-major
  __shared__ unsigned short Vt[128 * 20];   // V^T, stride 20 (pad: 8B-aligned, conflict-free reads)
  const int tid = threadIdx.x;
  const int w = tid >> 6, lane = tid & 63;
  const int quad = lane >> 4, l15 = lane & 15;
  const int t0 = blockIdx.x * 16;
  const int g = blockIdx.y;
  const int h = g * 4 + w;
  const f32x4 fzero = {0.f, 0.f, 0.f, 0.f};

  short8 qf[4];   // B-operand of QK^T: Q[m=l15][d=quad*8+j+32*kb]
  {
    const unsigned short* qrow = qp + (size_t)(t0 + l15) * 2048 + h * 128 + quad * 8;
#pragma unroll
    for (int kb = 0; kb < 4; kb++) qf[kb] = *(const short8*)(qrow + kb * 32);
  }

  f32x4 oacc[8];  // O^T[d=db*16+quad*4+r][m=l15]
#pragma unroll
  for (int d = 0; d < 8; d++) oacc[d] = fzero;
  float Mrow = -3.0e38f, Lrow = 0.f;
  const float scale = 0.088388347648318447f;  // 1/sqrt(128)

  const int s_begin = (t0 > 512) ? (t0 - 512) : 0;
  const int nch = ((t0 - s_begin) >> 4) + 1;

  for (int c = 0; c < nch; ++c) {
    const int s0 = s_begin + c * 16;
    __syncthreads();  // previous chunk's LDS reads done
    // K chunk: 4 waves x 1KB, global_load_lds width 16
    glds16(kp + (size_t)(s0 + w * 4 + (lane >> 4)) * 512 + g * 128 + (lane & 15) * 8,
           &Ks[w * 512]);
    // V chunk staged transposed via VGPR
    {
      const int s = tid >> 4, d0 = (tid & 15) * 8;
      short8 vv = *(const short8*)(vp + (size_t)(s0 + s) * 3072 + g * 128 + d0);
#pragma unroll
      for (int j = 0; j < 8; j++) Vt[(d0 + j) * 20 + s] = (unsigned short)vv[j];
    }
    __syncthreads();

    // S^T chunk: 16 keys x 16 queries
    f32x4 sacc = fzero;
#pragma unroll
    for (int kb = 0; kb < 4; kb++) {
      short8 kf = *(const short8*)&Ks[l15 * 128 + kb * 32 + quad * 8];
      sacc = __builtin_amdgcn_mfma_f32_16x16x32_bf16(kf, qf[kb], sacc, 0, 0, 0);
    }

    // mask + online softmax (column m = l15; rows s across quads+regs)
    float pvv[4];
    float cmax = -3.0e38f;
    const int t = t0 + l15;
#pragma unroll
    for (int r = 0; r < 4; r++) {
      const int s = s0 + quad * 4 + r;
      const bool ok = (s <= t) && (t - s <= 512);
      const float val = ok ? sacc[r] * scale : -3.0e38f;
      pvv[r] = val;
      cmax = fmaxf(cmax, val);
    }
    cmax = fmaxf(cmax, __shfl_xor(cmax, 16));
    cmax = fmaxf(cmax, __shfl_xor(cmax, 32));
    const float Mnew = fmaxf(Mrow, cmax);
    const float alpha = __expf(Mrow - Mnew);
    Mrow = Mnew;
    float csum = 0.f;
    short4_t pb;  // P^T B-operand: k=s=quad*4+j, n=m=l15 — exactly what this lane holds
#pragma unroll
    for (int r = 0; r < 4; r++) {
      const float p = __expf(pvv[r] - Mnew);
      csum += p;
      pb[r] = (short)f2b(p);
    }
    csum += __shfl_xor(csum, 16);
    csum += __shfl_xor(csum, 32);
    Lrow = Lrow * alpha + csum;

#pragma unroll
    for (int db = 0; db < 8; db++) {
      oacc[db][0] *= alpha; oacc[db][1] *= alpha;
      oacc[db][2] *= alpha; oacc[db][3] *= alpha;
      short4_t vf = *(const short4_t*)&Vt[(db * 16 + l15) * 20 + quad * 4];
      oacc[db] = __builtin_amdgcn_mfma_f32_16x16x16bf16_1k(vf, pb, oacc[db], 0, 0, 0);
    }
  }

  const float invL = 1.f / Lrow;
  unsigned short* orow = op + (size_t)(t0 + l15) * 2048 + h * 128;
#pragma unroll
  for (int db = 0; db < 8; db++) {
    u16x4 o;
#pragma unroll
    for (int r = 0; r < 4; r++) o[r] = f2b(oacc[db][r] * invL);
    *(u16x4*)(orow + db * 16 + quad * 4) = o;
  }
}

// ---------------------------------------------------------------- launch
extern "C" void kernel_launch(void* const* d_in, const int* in_sizes, int n_in,
                              void* d_out, int out_size, void* d_ws, size_t ws_size,
                              hipStream_t stream) {
  const float* x  = (const float*)d_in[0];
  const float* wq = (const float*)d_in[1];
  const float* wk = (const float*)d_in[2];
  const float* wv = (const float*)d_in[3];
  const float* wo = (const float*)d_in[4];
  float* out = (float*)d_out;
  char* ws = (char*)d_ws;

  // workspace map (80 MB total); attn output aliases x_bf16 (dead after gemm1)
  unsigned short* xb    = (unsigned short*)(ws + 0);           // 16,777,216 B
  unsigned short* wqkv  = (unsigned short*)(ws + 16777216);    // 12,582,912 B
  unsigned short* wob   = (unsigned short*)(ws + 29360128);    //  8,388,608 B
  unsigned short* qkv   = (unsigned short*)(ws + 37748736);    // 25,165,824 B
  unsigned short* qb    = (unsigned short*)(ws + 62914560);    // 16,777,216 B
  unsigned short* kb    = (unsigned short*)(ws + 79691776);    //  4,194,304 B
  unsigned short* attnb = xb;

  cast_f32_bf16<<<8192, 256, 0, stream>>>(x, xb, 2097152);
  cast_f32_bf16<<<4096, 256, 0, stream>>>(wq, wqkv, 1048576);
  cast_f32_bf16<<<1024, 256, 0, stream>>>(wk, wqkv + 4194304, 262144);
  cast_f32_bf16<<<1024, 256, 0, stream>>>(wv, wqkv + 5242880, 262144);
  cast_f32_bf16<<<4096, 256, 0, stream>>>(wo, wob, 1048576);

  // qkv = x @ [wq;wk;wv]^T   (4096 x 3072, K=2048), bf16 out
  gemm_bt<true><<<dim3(32, 24), 256, 0, stream>>>(xb, wqkv, qkv, 4096, 3072, 2048);

  rope_kernel<<<20480, 256, 0, stream>>>(qkv, qb, kb);

  // windowed GQA attention; v read in-place from qkv (col offset 2560, stride 3072)
  attn_fwd<<<dim3(256, 4), 256, 0, stream>>>(qb, kb, qkv + 2560, attnb);

  // out = attn @ wo^T  (4096 x 2048, K=2048), fp32 out
  gemm_bt<false><<<dim3(32, 16), 256, 0, stream>>>(attnb, wob, out, 4096, 2048, 2048);
}

// Round 3
// 303.513 us; speedup vs baseline: 1.1342x; 1.1342x over previous
//
#include <hip/hip_runtime.h>

typedef __attribute__((ext_vector_type(8))) short short8;
typedef __attribute__((ext_vector_type(4))) short short4_t;
typedef __attribute__((ext_vector_type(4))) float f32x4;
typedef __attribute__((ext_vector_type(4))) unsigned short u16x4;

__device__ __forceinline__ unsigned short f2b(float f) {
  unsigned int u = __float_as_uint(f);
  u += 0x7fffu + ((u >> 16) & 1u);   // RNE
  return (unsigned short)(u >> 16);
}
__device__ __forceinline__ float b2f(unsigned short s) {
  return __uint_as_float(((unsigned int)s) << 16);
}
__device__ __forceinline__ void glds16(const void* g, void* l) {
  __builtin_amdgcn_global_load_lds(
      (const __attribute__((address_space(1))) unsigned int*)g,
      (__attribute__((address_space(3))) unsigned int*)l, 16, 0, 0);
}

// ---------------------------------------------------------------- casts
__global__ __launch_bounds__(256) void cast_f32_bf16(const float* __restrict__ src,
                                                     unsigned short* __restrict__ dst,
                                                     int n4) {
  int i = blockIdx.x * 256 + threadIdx.x;
  if (i >= n4) return;
  f32x4 v = *(const f32x4*)(src + (size_t)i * 4);
  u16x4 o;
  o[0] = f2b(v[0]); o[1] = f2b(v[1]); o[2] = f2b(v[2]); o[3] = f2b(v[3]);
  *(u16x4*)(dst + (size_t)i * 4) = o;
}

// ------------------------------------------------- GEMM C = A * B^T (m97 structure)
template <bool BF16_OUT>
__global__ __launch_bounds__(256) void gemm_bt(const unsigned short* __restrict__ A,
                                               const unsigned short* __restrict__ B,
                                               void* __restrict__ Cout,
                                               int M, int N, int K) {
  __shared__ unsigned short As[128 * 32];
  __shared__ unsigned short Bs[128 * 32];
  const int tid = threadIdx.x;
  const int w = tid >> 6, lane = tid & 63;
  const int quad = lane >> 4, l15 = lane & 15;
  const int m0 = blockIdx.x * 128, n0 = blockIdx.y * 128;
  const int mbase = (w >> 1) * 64, nbase = (w & 1) * 64;
  const f32x4 fzero = {0.f, 0.f, 0.f, 0.f};

  f32x4 acc[4][4];
#pragma unroll
  for (int i = 0; i < 4; i++)
#pragma unroll
    for (int j = 0; j < 4; j++) acc[i][j] = fzero;

  const int srow = w * 16 + (lane >> 2);
  const int scol = (lane & 3) * 8;
  const unsigned short* Ag0 = A + (size_t)(m0 + srow) * K + scol;
  const unsigned short* Ag1 = Ag0 + (size_t)64 * K;
  const unsigned short* Bg0 = B + (size_t)(n0 + srow) * K + scol;
  const unsigned short* Bg1 = Bg0 + (size_t)64 * K;

  for (int k0 = 0; k0 < K; k0 += 32) {
    __syncthreads();
    glds16(Ag0 + k0, &As[w * 512]);
    glds16(Ag1 + k0, &As[2048 + w * 512]);
    glds16(Bg0 + k0, &Bs[w * 512]);
    glds16(Bg1 + k0, &Bs[2048 + w * 512]);
    __syncthreads();
    short8 af[4], bf[4];
#pragma unroll
    for (int mi = 0; mi < 4; mi++)
      af[mi] = *(const short8*)&As[(mbase + mi * 16 + l15) * 32 + quad * 8];
#pragma unroll
    for (int ni = 0; ni < 4; ni++)
      bf[ni] = *(const short8*)&Bs[(nbase + ni * 16 + l15) * 32 + quad * 8];
#pragma unroll
    for (int mi = 0; mi < 4; mi++)
#pragma unroll
      for (int ni = 0; ni < 4; ni++)
        acc[mi][ni] = __builtin_amdgcn_mfma_f32_16x16x32_bf16(af[mi], bf[ni], acc[mi][ni], 0, 0, 0);
  }

#pragma unroll
  for (int mi = 0; mi < 4; mi++)
#pragma unroll
    for (int ni = 0; ni < 4; ni++) {
      const int row = m0 + mbase + mi * 16 + quad * 4;
      const int col = n0 + nbase + ni * 16 + l15;
#pragma unroll
      for (int r = 0; r < 4; r++) {
        if (BF16_OUT)
          ((unsigned short*)Cout)[(size_t)(row + r) * N + col] = f2b(acc[mi][ni][r]);
        else
          ((float*)Cout)[(size_t)(row + r) * N + col] = acc[mi][ni][r];
      }
    }
}

// ---------------------------------------------------------------- RoPE (q + k)
__global__ __launch_bounds__(256) void rope_kernel(const unsigned short* __restrict__ qkv,
                                                   unsigned short* __restrict__ qo,
                                                   unsigned short* __restrict__ ko) {
  int idx = blockIdx.x * 256 + threadIdx.x;   // T*20*64 threads
  int t = idx / 1280;
  int rem = idx - t * 1280;
  int h = rem >> 6, i = rem & 63;
  const unsigned short* base = qkv + (size_t)t * 3072;
  unsigned short* dst;
  float x1, x2;
  if (h < 16) {
    x1 = b2f(base[h * 128 + i]);
    x2 = b2f(base[h * 128 + 64 + i]);
    dst = qo + (size_t)t * 2048 + h * 128;
  } else {
    int hk = h - 16;
    x1 = b2f(base[2048 + hk * 128 + i]);
    x2 = b2f(base[2048 + hk * 128 + 64 + i]);
    dst = ko + (size_t)t * 512 + hk * 128;
  }
  const float c2 = 0.20762050593045889f;      // log2(10000)/64
  float inv = exp2f(-(float)i * c2);
  float ang = (float)t * inv;
  float sn, cs;
  sincosf(ang, &sn, &cs);
  dst[i]      = f2b(x1 * cs - x2 * sn);
  dst[64 + i] = f2b(x1 * sn + x2 * cs);
}

// ---------------------------------------------------------------- V transpose
// qkv v-part (stride 3072, offset 2560): v[t][g*128+d] -> vt[g][d][t] (4,128,4096)
__global__ __launch_bounds__(256) void vtrans(const unsigned short* __restrict__ vp,
                                              unsigned short* __restrict__ vt) {
  __shared__ unsigned short tile[128 * 68];   // [d][t], stride 68 (8B-aligned rows)
  const int g = blockIdx.y;
  const int tb = blockIdx.x * 64;
  const int tid = threadIdx.x;
  const int tl = tid >> 4, d0 = (tid & 15) * 8;
#pragma unroll
  for (int rep = 0; rep < 4; rep++) {
    const int t = rep * 16 + tl;
    short8 v = *(const short8*)(vp + (size_t)(tb + t) * 3072 + g * 128 + d0);
#pragma unroll
    for (int j = 0; j < 8; j++) tile[(d0 + j) * 68 + t] = (unsigned short)v[j];
  }
  __syncthreads();
  const int d = tid >> 1, half = tid & 1;
  const unsigned short* src = &tile[d * 68 + half * 32];
  unsigned short* dst = vt + ((size_t)(g * 128 + d) * 4096 + tb + half * 32);
#pragma unroll
  for (int c = 0; c < 8; c++)          // 8 x short4 = full 32-element half-row
    *(short4_t*)(dst + c * 4) = *(const short4_t*)(src + c * 4);
}

// ------------------------------------------------------------ windowed GQA attention
// Block: 4 waves = 4 q-heads of one kv group; 32 queries/block, 32-key chunks.
// S^T tiles computed with PERMUTED key rows (A row m <-> key 8*(m>>2)+4*kt+(m&3)) so
// P^T lands exactly in the mfma_16x16x32 B-operand layout (k=quad*8+j <-> key s0+quad*8+j).
// K staged as [kb][key][32d] slabs, V^T as [d][32keys]: both b128-read at the LDS floor.
// Double-buffered LDS, one barrier per chunk, glds prefetch issued right after barrier.
__global__ __launch_bounds__(256) void attn_fwd(const unsigned short* __restrict__ qp,
                                                const unsigned short* __restrict__ kp,
                                                const unsigned short* __restrict__ vtg,
                                                unsigned short* __restrict__ op) {
  __shared__ unsigned short Ks[2][4][1024];   // [buf][kb][key*32+d']
  __shared__ unsigned short Vt[2][4096];      // [buf][d*32+key]
  const int tid = threadIdx.x;
  const int w = tid >> 6, lane = tid & 63;
  const int quad = lane >> 4, l15 = lane & 15;
  const int t0 = blockIdx.x * 32;
  const int g = blockIdx.y;
  const int h = g * 4 + w;
  const f32x4 fzero = {0.f, 0.f, 0.f, 0.f};
  const float scale = 0.088388347648318447f;  // 1/sqrt(128)

  // Q fragments qf[kb][qt]: B-operand, n=query=l15, k=d=kb*32+quad*8+j
  short8 qf[4][2];
#pragma unroll
  for (int qt = 0; qt < 2; qt++) {
    const unsigned short* qrow = qp + (size_t)(t0 + qt * 16 + l15) * 2048 + h * 128 + quad * 8;
#pragma unroll
    for (int kb = 0; kb < 4; kb++) qf[kb][qt] = *(const short8*)(qrow + kb * 32);
  }

  f32x4 oacc[8][2];
#pragma unroll
  for (int db = 0; db < 8; db++) { oacc[db][0] = fzero; oacc[db][1] = fzero; }
  float Mrow[2] = {-3.0e38f, -3.0e38f}, Lrow[2] = {0.f, 0.f};

  const int s_begin = (t0 >= 512) ? (t0 - 512) : 0;
  const int nch = ((t0 - s_begin) >> 5) + 1;

  const int r4 = lane >> 2, c4 = lane & 3;
  // stage chunk s0 into buf b: per wave 2 glds16 for K (kb=w slab) + 2 for V^T
#define ATTN_STAGE(s0_, b_)                                                              \
  {                                                                                      \
    const int s0v = (s0_);                                                               \
    _Pragma("unroll")                                                                    \
    for (int p = 0; p < 2; p++) {                                                        \
      glds16(kp + (size_t)(s0v + p * 16 + r4) * 512 + g * 128 + w * 32 + c4 * 8,         \
             &Ks[b_][w][p * 512]);                                                       \
      glds16(vtg + (size_t)(g * 128 + w * 32 + p * 16 + r4) * 4096 + s0v + c4 * 8,       \
             &Vt[b_][w * 1024 + p * 512]);                                               \
    }                                                                                    \
  }

  ATTN_STAGE(s_begin, 0);

  for (int c = 0; c < nch; ++c) {
    const int s0 = s_begin + c * 32;
    const int b = c & 1;
    __syncthreads();                       // drain glds for chunk c; align waves
    if (c + 1 < nch) ATTN_STAGE(s_begin + (c + 1) * 32, (c + 1) & 1);

    // ---- S^T = K * Q^T, permuted key rows
    f32x4 sacc[2][2];
    sacc[0][0] = fzero; sacc[0][1] = fzero; sacc[1][0] = fzero; sacc[1][1] = fzero;
    const int permBase = ((l15 >> 2) << 3) + (l15 & 3);   // + 4*kt
#pragma unroll
    for (int kb = 0; kb < 4; kb++) {
      short8 af0 = *(const short8*)&Ks[b][kb][(permBase + 0) * 32 + quad * 8];
      short8 af1 = *(const short8*)&Ks[b][kb][(permBase + 4) * 32 + quad * 8];
      sacc[0][0] = __builtin_amdgcn_mfma_f32_16x16x32_bf16(af0, qf[kb][0], sacc[0][0], 0, 0, 0);
      sacc[0][1] = __builtin_amdgcn_mfma_f32_16x16x32_bf16(af0, qf[kb][1], sacc[0][1], 0, 0, 0);
      sacc[1][0] = __builtin_amdgcn_mfma_f32_16x16x32_bf16(af1, qf[kb][0], sacc[1][0], 0, 0, 0);
      sacc[1][1] = __builtin_amdgcn_mfma_f32_16x16x32_bf16(af1, qf[kb][1], sacc[1][1], 0, 0, 0);
    }

    // ---- masked online softmax (per qt); key for (kt,r) = s0 + quad*8 + kt*4 + r
    short8 pb[2];
    float alpha[2];
#pragma unroll
    for (int qt = 0; qt < 2; qt++) {
      const int tq = t0 + qt * 16 + l15;
      float vals[8];
      float cmax = -3.0e38f;
#pragma unroll
      for (int kt = 0; kt < 2; kt++)
#pragma unroll
        for (int r = 0; r < 4; r++) {
          const int s = s0 + quad * 8 + kt * 4 + r;
          const bool ok = (unsigned)(tq - s) <= 512u;
          const float v = ok ? sacc[kt][qt][r] * scale : -3.0e38f;
          vals[kt * 4 + r] = v;
          cmax = fmaxf(cmax, v);
        }
      cmax = fmaxf(cmax, __shfl_xor(cmax, 16));
      cmax = fmaxf(cmax, __shfl_xor(cmax, 32));
      const float Mnew = fmaxf(Mrow[qt], cmax);
      alpha[qt] = __expf(Mrow[qt] - Mnew);
      Mrow[qt] = Mnew;
      float csum = 0.f;
#pragma unroll
      for (int j = 0; j < 8; j++) {
        const float p = __expf(vals[j] - Mnew);
        csum += p;
        pb[qt][j] = (short)f2b(p);
      }
      csum += __shfl_xor(csum, 16);
      csum += __shfl_xor(csum, 32);
      Lrow[qt] = Lrow[qt] * alpha[qt] + csum;
    }

    // ---- O^T += V^T * P^T  (A = V^T[d][key], B = pb)
#pragma unroll
    for (int db = 0; db < 8; db++) {
      short8 vf = *(const short8*)&Vt[b][(db * 16 + l15) * 32 + quad * 8];
#pragma unroll
      for (int qt = 0; qt < 2; qt++) {
        oacc[db][qt][0] *= alpha[qt]; oacc[db][qt][1] *= alpha[qt];
        oacc[db][qt][2] *= alpha[qt]; oacc[db][qt][3] *= alpha[qt];
        oacc[db][qt] = __builtin_amdgcn_mfma_f32_16x16x32_bf16(vf, pb[qt], oacc[db][qt], 0, 0, 0);
      }
    }
  }
#undef ATTN_STAGE

#pragma unroll
  for (int qt = 0; qt < 2; qt++) {
    const float invL = 1.f / Lrow[qt];
    unsigned short* orow = op + (size_t)(t0 + qt * 16 + l15) * 2048 + h * 128;
#pragma unroll
    for (int db = 0; db < 8; db++) {
      u16x4 o;
#pragma unroll
      for (int r = 0; r < 4; r++) o[r] = f2b(oacc[db][qt][r] * invL);
      *(u16x4*)(orow + db * 16 + quad * 4) = o;
    }
  }
}

// ---------------------------------------------------------------- launch
extern "C" void kernel_launch(void* const* d_in, const int* in_sizes, int n_in,
                              void* d_out, int out_size, void* d_ws, size_t ws_size,
                              hipStream_t stream) {
  const float* x  = (const float*)d_in[0];
  const float* wq = (const float*)d_in[1];
  const float* wk = (const float*)d_in[2];
  const float* wv = (const float*)d_in[3];
  const float* wo = (const float*)d_in[4];
  float* out = (float*)d_out;
  char* ws = (char*)d_ws;

  // workspace map (80 MB); attnb aliases xb (dead after gemm1),
  // vtg aliases wqkv (dead after gemm1)
  unsigned short* xb    = (unsigned short*)(ws + 0);           // 16,777,216 B
  unsigned short* wqkv  = (unsigned short*)(ws + 16777216);    // 12,582,912 B
  unsigned short* wob   = (unsigned short*)(ws + 29360128);    //  8,388,608 B
  unsigned short* qkv   = (unsigned short*)(ws + 37748736);    // 25,165,824 B
  unsigned short* qb    = (unsigned short*)(ws + 62914560);    // 16,777,216 B
  unsigned short* kb    = (unsigned short*)(ws + 79691776);    //  4,194,304 B
  unsigned short* attnb = xb;
  unsigned short* vtg   = wqkv;                                //  4,194,304 B

  cast_f32_bf16<<<8192, 256, 0, stream>>>(x, xb, 2097152);
  cast_f32_bf16<<<4096, 256, 0, stream>>>(wq, wqkv, 1048576);
  cast_f32_bf16<<<1024, 256, 0, stream>>>(wk, wqkv + 4194304, 262144);
  cast_f32_bf16<<<1024, 256, 0, stream>>>(wv, wqkv + 5242880, 262144);
  cast_f32_bf16<<<4096, 256, 0, stream>>>(wo, wob, 1048576);

  // qkv = x @ [wq;wk;wv]^T   (4096 x 3072, K=2048), bf16 out
  gemm_bt<true><<<dim3(32, 24), 256, 0, stream>>>(xb, wqkv, qkv, 4096, 3072, 2048);

  rope_kernel<<<20480, 256, 0, stream>>>(qkv, qb, kb);
  vtrans<<<dim3(64, 4), 256, 0, stream>>>(qkv + 2560, vtg);

  attn_fwd<<<dim3(128, 4), 256, 0, stream>>>(qb, kb, vtg, attnb);

  // out = attn @ wo^T  (4096 x 2048, K=2048), fp32 out
  gemm_bt<false><<<dim3(32, 16), 256, 0, stream>>>(attnb, wob, out, 4096, 2048, 2048);
}

// Round 4
// 291.710 us; speedup vs baseline: 1.1801x; 1.0405x over previous
//
#include <hip/hip_runtime.h>

typedef __attribute__((ext_vector_type(8))) short short8;
typedef __attribute__((ext_vector_type(4))) short short4_t;
typedef __attribute__((ext_vector_type(4))) float f32x4;
typedef __attribute__((ext_vector_type(4))) unsigned short u16x4;

__device__ __forceinline__ unsigned short f2b(float f) {
  unsigned int u = __float_as_uint(f);
  u += 0x7fffu + ((u >> 16) & 1u);   // RNE
  return (unsigned short)(u >> 16);
}
__device__ __forceinline__ float b2f(unsigned short s) {
  return __uint_as_float(((unsigned int)s) << 16);
}
__device__ __forceinline__ void glds16(const void* g, void* l) {
  __builtin_amdgcn_global_load_lds(
      (const __attribute__((address_space(1))) unsigned int*)g,
      (__attribute__((address_space(3))) unsigned int*)l, 16, 0, 0);
}

// ------------------------------------------------- fused cast: all 5 inputs -> bf16
// dst regions laid out contiguously in ws: [x | wq | wk | wv | wo], float4-indexed.
__global__ __launch_bounds__(256) void cast_all(const float* __restrict__ x,
                                                const float* __restrict__ wq,
                                                const float* __restrict__ wk,
                                                const float* __restrict__ wv,
                                                const float* __restrict__ wo,
                                                unsigned short* __restrict__ dst) {
  const int i = blockIdx.x * 256 + threadIdx.x;   // < 4,718,592 (grid exact)
  const float* s;
  int off;
  if (i < 2097152)      { s = x;  off = i; }
  else if (i < 3145728) { s = wq; off = i - 2097152; }
  else if (i < 3407872) { s = wk; off = i - 3145728; }
  else if (i < 3670016) { s = wv; off = i - 3407872; }
  else                  { s = wo; off = i - 3670016; }
  f32x4 v = ((const f32x4*)s)[off];
  u16x4 o;
  o[0] = f2b(v[0]); o[1] = f2b(v[1]); o[2] = f2b(v[2]); o[3] = f2b(v[3]);
  ((u16x4*)dst)[i] = o;
}

// ------------------------------------------------- GEMM1 + fused RoPE/V^T epilogue
// C = x @ Wqkv^T (4096 x 3072, K=2048). Each 128-col n-tile is exactly one head.
// Wave column groups ngrp = (w&1)*2 + (ni&1) + (ni>>1)*4: each thread holds rope
// partners (d, d+64) as acc[mi][ni] / acc[mi][ni+2] (ni<2) -> thread-local RoPE.
__global__ __launch_bounds__(256) void gemm_qkv(const unsigned short* __restrict__ A,
                                                const unsigned short* __restrict__ B,
                                                unsigned short* __restrict__ qb,
                                                unsigned short* __restrict__ kb,
                                                unsigned short* __restrict__ vtg) {
  const int K = 2048;
  __shared__ unsigned short As[128 * 32];
  __shared__ unsigned short Bs[128 * 32];
  const int tid = threadIdx.x;
  const int w = tid >> 6, lane = tid & 63;
  const int quad = lane >> 4, l15 = lane & 15;
  const int m0 = blockIdx.x * 128;
  const int nt = blockIdx.y;                 // head tile: 0-15 q, 16-19 k, 20-23 v
  const int n0 = nt * 128;
  const int mbase = (w >> 1) * 64;
  const f32x4 fzero = {0.f, 0.f, 0.f, 0.f};

  f32x4 acc[4][4];
#pragma unroll
  for (int i = 0; i < 4; i++)
#pragma unroll
    for (int j = 0; j < 4; j++) acc[i][j] = fzero;

  const int srow = w * 16 + (lane >> 2);
  const int scol = (lane & 3) * 8;
  const unsigned short* Ag0 = A + (size_t)(m0 + srow) * K + scol;
  const unsigned short* Ag1 = Ag0 + (size_t)64 * K;
  const unsigned short* Bg0 = B + (size_t)(n0 + srow) * K + scol;
  const unsigned short* Bg1 = Bg0 + (size_t)64 * K;

  for (int k0 = 0; k0 < K; k0 += 32) {
    __syncthreads();
    glds16(Ag0 + k0, &As[w * 512]);
    glds16(Ag1 + k0, &As[2048 + w * 512]);
    glds16(Bg0 + k0, &Bs[w * 512]);
    glds16(Bg1 + k0, &Bs[2048 + w * 512]);
    __syncthreads();
    short8 af[4], bf[4];
#pragma unroll
    for (int mi = 0; mi < 4; mi++)
      af[mi] = *(const short8*)&As[(mbase + mi * 16 + l15) * 32 + quad * 8];
#pragma unroll
    for (int ni = 0; ni < 4; ni++) {
      const int ngrp = (w & 1) * 2 + (ni & 1) + (ni >> 1) * 4;
      bf[ni] = *(const short8*)&Bs[(ngrp * 16 + l15) * 32 + quad * 8];
    }
#pragma unroll
    for (int mi = 0; mi < 4; mi++)
#pragma unroll
      for (int ni = 0; ni < 4; ni++)
        acc[mi][ni] = __builtin_amdgcn_mfma_f32_16x16x32_bf16(af[mi], bf[ni], acc[mi][ni], 0, 0, 0);
  }

  if (nt >= 20) {
    // ---- V tile: store transposed into vtg[g][d][t]
    const int g = nt - 20;
#pragma unroll
    for (int mi = 0; mi < 4; mi++) {
      const int tb = m0 + mbase + mi * 16 + quad * 4;
#pragma unroll
      for (int ni = 0; ni < 4; ni++) {
        const int d = ((w & 1) * 2 + (ni & 1) + (ni >> 1) * 4) * 16 + l15;
        u16x4 o;
#pragma unroll
        for (int r = 0; r < 4; r++) o[r] = f2b(acc[mi][ni][r]);
        *(u16x4*)(vtg + (size_t)(g * 128 + d) * 4096 + tb) = o;
      }
    }
  } else {
    // ---- Q/K tile: thread-local RoPE, write to qb or kb
    unsigned short* dst;
    int stride, hoff;
    if (nt < 16) { dst = qb; stride = 2048; hoff = nt * 128; }
    else         { dst = kb; stride = 512;  hoff = (nt - 16) * 128; }
    const float c2 = 0.20762050593045889f;   // log2(10000)/64
#pragma unroll
    for (int ni = 0; ni < 2; ni++) {
      const int i = (w & 1) * 32 + ni * 16 + l15;   // rope dim, < 64
      const float inv = exp2f(-(float)i * c2);
#pragma unroll
      for (int mi = 0; mi < 4; mi++) {
#pragma unroll
        for (int r = 0; r < 4; r++) {
          const int t = m0 + mbase + mi * 16 + quad * 4 + r;
          float sn, cs;
          sincosf((float)t * inv, &sn, &cs);
          const float x1 = acc[mi][ni][r], x2 = acc[mi][ni + 2][r];
          unsigned short* p = dst + (size_t)t * stride + hoff + i;
          p[0]  = f2b(x1 * cs - x2 * sn);
          p[64] = f2b(x1 * sn + x2 * cs);
        }
      }
    }
  }
}

// ------------------------------------------------- GEMM C = A * B^T (fp32 out, m97)
__global__ __launch_bounds__(256) void gemm_bt(const unsigned short* __restrict__ A,
                                               const unsigned short* __restrict__ B,
                                               float* __restrict__ Cout,
                                               int M, int N, int K) {
  __shared__ unsigned short As[128 * 32];
  __shared__ unsigned short Bs[128 * 32];
  const int tid = threadIdx.x;
  const int w = tid >> 6, lane = tid & 63;
  const int quad = lane >> 4, l15 = lane & 15;
  const int m0 = blockIdx.x * 128, n0 = blockIdx.y * 128;
  const int mbase = (w >> 1) * 64, nbase = (w & 1) * 64;
  const f32x4 fzero = {0.f, 0.f, 0.f, 0.f};

  f32x4 acc[4][4];
#pragma unroll
  for (int i = 0; i < 4; i++)
#pragma unroll
    for (int j = 0; j < 4; j++) acc[i][j] = fzero;

  const int srow = w * 16 + (lane >> 2);
  const int scol = (lane & 3) * 8;
  const unsigned short* Ag0 = A + (size_t)(m0 + srow) * K + scol;
  const unsigned short* Ag1 = Ag0 + (size_t)64 * K;
  const unsigned short* Bg0 = B + (size_t)(n0 + srow) * K + scol;
  const unsigned short* Bg1 = Bg0 + (size_t)64 * K;

  for (int k0 = 0; k0 < K; k0 += 32) {
    __syncthreads();
    glds16(Ag0 + k0, &As[w * 512]);
    glds16(Ag1 + k0, &As[2048 + w * 512]);
    glds16(Bg0 + k0, &Bs[w * 512]);
    glds16(Bg1 + k0, &Bs[2048 + w * 512]);
    __syncthreads();
    short8 af[4], bf[4];
#pragma unroll
    for (int mi = 0; mi < 4; mi++)
      af[mi] = *(const short8*)&As[(mbase + mi * 16 + l15) * 32 + quad * 8];
#pragma unroll
    for (int ni = 0; ni < 4; ni++)
      bf[ni] = *(const short8*)&Bs[(nbase + ni * 16 + l15) * 32 + quad * 8];
#pragma unroll
    for (int mi = 0; mi < 4; mi++)
#pragma unroll
      for (int ni = 0; ni < 4; ni++)
        acc[mi][ni] = __builtin_amdgcn_mfma_f32_16x16x32_bf16(af[mi], bf[ni], acc[mi][ni], 0, 0, 0);
  }

#pragma unroll
  for (int mi = 0; mi < 4; mi++)
#pragma unroll
    for (int ni = 0; ni < 4; ni++) {
      const int row = m0 + mbase + mi * 16 + quad * 4;
      const int col = n0 + nbase + ni * 16 + l15;
#pragma unroll
      for (int r = 0; r < 4; r++)
        Cout[(size_t)(row + r) * N + col] = acc[mi][ni][r];
    }
}

// ------------------------------------------------------------ windowed GQA attention
// Block: 8 waves, 64 queries, one kv group. wave w: head g*4+(w&3), query-half w>>2.
// All 8 waves share one K/V staging stream (halved staging vs 4-wave blocks).
// Robust softmax: masked = -INF, Mrow init -1e30 (fully-masked chunks give p=0).
__global__ __launch_bounds__(512) void attn_fwd(const unsigned short* __restrict__ qp,
                                                const unsigned short* __restrict__ kp,
                                                const unsigned short* __restrict__ vtg,
                                                unsigned short* __restrict__ op) {
  __shared__ unsigned short Ks[2][4][1024];   // [buf][kb][key*32+d']
  __shared__ unsigned short Vt[2][4096];      // [buf][d*32+key]
  const int tid = threadIdx.x;
  const int w = tid >> 6, lane = tid & 63;
  const int quad = lane >> 4, l15 = lane & 15;
  const int t0 = blockIdx.x * 64;
  const int g = blockIdx.y;
  const int h = g * 4 + (w & 3);
  const int t0w = t0 + (w >> 2) * 32;         // this wave's 32-query base
  const f32x4 fzero = {0.f, 0.f, 0.f, 0.f};
  const float scale = 0.088388347648318447f;  // 1/sqrt(128)
  const float NEG_INF = -__builtin_inff();

  short8 qf[4][2];
#pragma unroll
  for (int qt = 0; qt < 2; qt++) {
    const unsigned short* qrow = qp + (size_t)(t0w + qt * 16 + l15) * 2048 + h * 128 + quad * 8;
#pragma unroll
    for (int kb = 0; kb < 4; kb++) qf[kb][qt] = *(const short8*)(qrow + kb * 32);
  }

  f32x4 oacc[8][2];
#pragma unroll
  for (int db = 0; db < 8; db++) { oacc[db][0] = fzero; oacc[db][1] = fzero; }
  float Mrow[2] = {-1.0e30f, -1.0e30f}, Lrow[2] = {0.f, 0.f};

  const int s_begin = (t0 >= 512) ? (t0 - 512) : 0;
  const int nch = ((t0 + 63 - s_begin) >> 5) + 1;

  const int r4 = lane >> 2, c4 = lane & 3;
  // wave w<4 stages K slab w; wave w>=4 stages V^T quarter (w-4). 2 glds16 each.
#define ATTN_STAGE(s0_, b_)                                                              \
  {                                                                                      \
    const int s0v = (s0_);                                                               \
    if (w < 4) {                                                                         \
      _Pragma("unroll")                                                                  \
      for (int p = 0; p < 2; p++)                                                        \
        glds16(kp + (size_t)(s0v + p * 16 + r4) * 512 + g * 128 + w * 32 + c4 * 8,       \
               &Ks[b_][w][p * 512]);                                                     \
    } else {                                                                             \
      const int wv = w - 4;                                                              \
      _Pragma("unroll")                                                                  \
      for (int p = 0; p < 2; p++)                                                        \
        glds16(vtg + (size_t)(g * 128 + wv * 32 + p * 16 + r4) * 4096 + s0v + c4 * 8,    \
               &Vt[b_][wv * 1024 + p * 512]);                                            \
    }                                                                                    \
  }

  ATTN_STAGE(s_begin, 0);

  for (int c = 0; c < nch; ++c) {
    const int s0 = s_begin + c * 32;
    const int b = c & 1;
    __syncthreads();                       // drain glds for chunk c (uniform)
    if (c + 1 < nch) ATTN_STAGE(s_begin + (c + 1) * 32, (c + 1) & 1);

    // wave-relevance: this wave's queries [t0w, t0w+31] vs keys [s0, s0+31]
    if (s0 + 31 >= t0w - 512 && s0 <= t0w + 31) {
      // ---- S^T = K * Q^T, permuted key rows
      f32x4 sacc[2][2];
      sacc[0][0] = fzero; sacc[0][1] = fzero; sacc[1][0] = fzero; sacc[1][1] = fzero;
      const int permBase = ((l15 >> 2) << 3) + (l15 & 3);   // + 4*kt
#pragma unroll
      for (int kb = 0; kb < 4; kb++) {
        short8 af0 = *(const short8*)&Ks[b][kb][(permBase + 0) * 32 + quad * 8];
        short8 af1 = *(const short8*)&Ks[b][kb][(permBase + 4) * 32 + quad * 8];
        sacc[0][0] = __builtin_amdgcn_mfma_f32_16x16x32_bf16(af0, qf[kb][0], sacc[0][0], 0, 0, 0);
        sacc[0][1] = __builtin_amdgcn_mfma_f32_16x16x32_bf16(af0, qf[kb][1], sacc[0][1], 0, 0, 0);
        sacc[1][0] = __builtin_amdgcn_mfma_f32_16x16x32_bf16(af1, qf[kb][0], sacc[1][0], 0, 0, 0);
        sacc[1][1] = __builtin_amdgcn_mfma_f32_16x16x32_bf16(af1, qf[kb][1], sacc[1][1], 0, 0, 0);
      }

      // ---- masked online softmax; key for (kt,r) = s0 + quad*8 + kt*4 + r
      short8 pb[2];
      float alpha[2];
#pragma unroll
      for (int qt = 0; qt < 2; qt++) {
        const int tq = t0w + qt * 16 + l15;
        float vals[8];
        float cmax = NEG_INF;
#pragma unroll
        for (int kt = 0; kt < 2; kt++)
#pragma unroll
          for (int r = 0; r < 4; r++) {
            const int s = s0 + quad * 8 + kt * 4 + r;
            const bool ok = (unsigned)(tq - s) <= 512u;
            const float v = ok ? sacc[kt][qt][r] * scale : NEG_INF;
            vals[kt * 4 + r] = v;
            cmax = fmaxf(cmax, v);
          }
        cmax = fmaxf(cmax, __shfl_xor(cmax, 16));
        cmax = fmaxf(cmax, __shfl_xor(cmax, 32));
        const float Mnew = fmaxf(Mrow[qt], cmax);
        alpha[qt] = __expf(Mrow[qt] - Mnew);
        Mrow[qt] = Mnew;
        float csum = 0.f;
#pragma unroll
        for (int j = 0; j < 8; j++) {
          const float p = __expf(vals[j] - Mnew);   // exp(-inf) = 0 for masked
          csum += p;
          pb[qt][j] = (short)f2b(p);
        }
        csum += __shfl_xor(csum, 16);
        csum += __shfl_xor(csum, 32);
        Lrow[qt] = Lrow[qt] * alpha[qt] + csum;
      }

      // ---- O^T += V^T * P^T
#pragma unroll
      for (int db = 0; db < 8; db++) {
        short8 vf = *(const short8*)&Vt[b][(db * 16 + l15) * 32 + quad * 8];
#pragma unroll
        for (int qt = 0; qt < 2; qt++) {
          oacc[db][qt][0] *= alpha[qt]; oacc[db][qt][1] *= alpha[qt];
          oacc[db][qt][2] *= alpha[qt]; oacc[db][qt][3] *= alpha[qt];
          oacc[db][qt] = __builtin_amdgcn_mfma_f32_16x16x32_bf16(vf, pb[qt], oacc[db][qt], 0, 0, 0);
        }
      }
    }
  }
#undef ATTN_STAGE

#pragma unroll
  for (int qt = 0; qt < 2; qt++) {
    const float invL = 1.f / Lrow[qt];
    unsigned short* orow = op + (size_t)(t0w + qt * 16 + l15) * 2048 + h * 128;
#pragma unroll
    for (int db = 0; db < 8; db++) {
      u16x4 o;
#pragma unroll
      for (int r = 0; r < 4; r++) o[r] = f2b(oacc[db][qt][r] * invL);
      *(u16x4*)(orow + db * 16 + quad * 4) = o;
    }
  }
}

// ---------------------------------------------------------------- launch
extern "C" void kernel_launch(void* const* d_in, const int* in_sizes, int n_in,
                              void* d_out, int out_size, void* d_ws, size_t ws_size,
                              hipStream_t stream) {
  const float* x  = (const float*)d_in[0];
  const float* wq = (const float*)d_in[1];
  const float* wk = (const float*)d_in[2];
  const float* wv = (const float*)d_in[3];
  const float* wo = (const float*)d_in[4];
  float* out = (float*)d_out;
  char* ws = (char*)d_ws;

  // workspace map (~63 MB); attnb aliases xb (dead after gemm_qkv)
  unsigned short* xb    = (unsigned short*)(ws + 0);           // 16,777,216 B
  unsigned short* wqkv  = (unsigned short*)(ws + 16777216);    // 12,582,912 B
  unsigned short* wob   = (unsigned short*)(ws + 29360128);    //  8,388,608 B
  unsigned short* qb    = (unsigned short*)(ws + 37748736);    // 16,777,216 B
  unsigned short* kbuf  = (unsigned short*)(ws + 54525952);    //  4,194,304 B
  unsigned short* vtg   = (unsigned short*)(ws + 58720256);    //  4,194,304 B
  unsigned short* attnb = xb;

  cast_all<<<18432, 256, 0, stream>>>(x, wq, wk, wv, wo, (unsigned short*)ws);

  // qkv proj + fused RoPE + fused V-transpose
  gemm_qkv<<<dim3(32, 24), 256, 0, stream>>>(xb, wqkv, qb, kbuf, vtg);

  attn_fwd<<<dim3(64, 4), 512, 0, stream>>>(qb, kbuf, vtg, attnb);

  // out = attn @ wo^T  (4096 x 2048, K=2048), fp32 out
  gemm_bt<<<dim3(32, 16), 256, 0, stream>>>(attnb, wob, out, 4096, 2048, 2048);
}

// Round 5
// 285.992 us; speedup vs baseline: 1.2037x; 1.0200x over previous
//
#include <hip/hip_runtime.h>

typedef __attribute__((ext_vector_type(8))) short short8;
typedef __attribute__((ext_vector_type(4))) short short4_t;
typedef __attribute__((ext_vector_type(4))) float f32x4;
typedef __attribute__((ext_vector_type(4))) unsigned short u16x4;

__device__ __forceinline__ unsigned short f2b(float f) {
  unsigned int u = __float_as_uint(f);
  u += 0x7fffu + ((u >> 16) & 1u);   // RNE
  return (unsigned short)(u >> 16);
}
__device__ __forceinline__ float b2f(unsigned short s) {
  return __uint_as_float(((unsigned int)s) << 16);
}
__device__ __forceinline__ void glds16(const void* g, void* l) {
  __builtin_amdgcn_global_load_lds(
      (const __attribute__((address_space(1))) unsigned int*)g,
      (__attribute__((address_space(3))) unsigned int*)l, 16, 0, 0);
}

// ------------------------------------------------- fused cast: all 5 inputs -> bf16
__global__ __launch_bounds__(256) void cast_all(const float* __restrict__ x,
                                                const float* __restrict__ wq,
                                                const float* __restrict__ wk,
                                                const float* __restrict__ wv,
                                                const float* __restrict__ wo,
                                                unsigned short* __restrict__ dst) {
  const int i = blockIdx.x * 256 + threadIdx.x;   // < 4,718,592 (grid exact)
  const float* s;
  int off;
  if (i < 2097152)      { s = x;  off = i; }
  else if (i < 3145728) { s = wq; off = i - 2097152; }
  else if (i < 3407872) { s = wk; off = i - 3145728; }
  else if (i < 3670016) { s = wv; off = i - 3407872; }
  else                  { s = wo; off = i - 3670016; }
  f32x4 v = ((const f32x4*)s)[off];
  u16x4 o;
  o[0] = f2b(v[0]); o[1] = f2b(v[1]); o[2] = f2b(v[2]); o[3] = f2b(v[3]);
  ((u16x4*)dst)[i] = o;
}

// ------------------------------------------------- GEMM1 + fused RoPE/V^T epilogue
// C = x @ Wqkv^T (4096 x 3072, K=2048). Each 128-col n-tile is exactly one head.
// Wave column groups ngrp = (w&1)*2 + (ni&1) + (ni>>1)*4: each thread holds rope
// partners (d, d+64) as acc[mi][ni] / acc[mi][ni+2] (ni<2) -> thread-local RoPE.
// RoPE trig via HW v_sin/v_cos on fract-reduced revolutions (NOT libm sincosf:
// its Payne-Hanek path drove VGPR 68->120 and cost ~26us in round 4).
__global__ __launch_bounds__(256) void gemm_qkv(const unsigned short* __restrict__ A,
                                                const unsigned short* __restrict__ B,
                                                unsigned short* __restrict__ qb,
                                                unsigned short* __restrict__ kb,
                                                unsigned short* __restrict__ vtg) {
  const int K = 2048;
  __shared__ unsigned short As[128 * 32];
  __shared__ unsigned short Bs[128 * 32];
  const int tid = threadIdx.x;
  const int w = tid >> 6, lane = tid & 63;
  const int quad = lane >> 4, l15 = lane & 15;
  const int m0 = blockIdx.x * 128;
  const int nt = blockIdx.y;                 // head tile: 0-15 q, 16-19 k, 20-23 v
  const int n0 = nt * 128;
  const int mbase = (w >> 1) * 64;
  const f32x4 fzero = {0.f, 0.f, 0.f, 0.f};

  f32x4 acc[4][4];
#pragma unroll
  for (int i = 0; i < 4; i++)
#pragma unroll
    for (int j = 0; j < 4; j++) acc[i][j] = fzero;

  const int srow = w * 16 + (lane >> 2);
  const int scol = (lane & 3) * 8;
  const unsigned short* Ag0 = A + (size_t)(m0 + srow) * K + scol;
  const unsigned short* Ag1 = Ag0 + (size_t)64 * K;
  const unsigned short* Bg0 = B + (size_t)(n0 + srow) * K + scol;
  const unsigned short* Bg1 = Bg0 + (size_t)64 * K;

  for (int k0 = 0; k0 < K; k0 += 32) {
    __syncthreads();
    glds16(Ag0 + k0, &As[w * 512]);
    glds16(Ag1 + k0, &As[2048 + w * 512]);
    glds16(Bg0 + k0, &Bs[w * 512]);
    glds16(Bg1 + k0, &Bs[2048 + w * 512]);
    __syncthreads();
    short8 af[4], bf[4];
#pragma unroll
    for (int mi = 0; mi < 4; mi++)
      af[mi] = *(const short8*)&As[(mbase + mi * 16 + l15) * 32 + quad * 8];
#pragma unroll
    for (int ni = 0; ni < 4; ni++) {
      const int ngrp = (w & 1) * 2 + (ni & 1) + (ni >> 1) * 4;
      bf[ni] = *(const short8*)&Bs[(ngrp * 16 + l15) * 32 + quad * 8];
    }
#pragma unroll
    for (int mi = 0; mi < 4; mi++)
#pragma unroll
      for (int ni = 0; ni < 4; ni++)
        acc[mi][ni] = __builtin_amdgcn_mfma_f32_16x16x32_bf16(af[mi], bf[ni], acc[mi][ni], 0, 0, 0);
  }

  if (nt >= 20) {
    // ---- V tile: store transposed into vtg[g][d][t]
    const int g = nt - 20;
#pragma unroll
    for (int mi = 0; mi < 4; mi++) {
      const int tb = m0 + mbase + mi * 16 + quad * 4;
#pragma unroll
      for (int ni = 0; ni < 4; ni++) {
        const int d = ((w & 1) * 2 + (ni & 1) + (ni >> 1) * 4) * 16 + l15;
        u16x4 o;
#pragma unroll
        for (int r = 0; r < 4; r++) o[r] = f2b(acc[mi][ni][r]);
        *(u16x4*)(vtg + (size_t)(g * 128 + d) * 4096 + tb) = o;
      }
    }
  } else {
    // ---- Q/K tile: thread-local RoPE, write to qb or kb
    unsigned short* dst;
    int stride, hoff;
    if (nt < 16) { dst = qb; stride = 2048; hoff = nt * 128; }
    else         { dst = kb; stride = 512;  hoff = (nt - 16) * 128; }
    const float c2 = 0.20762050593045889f;   // log2(10000)/64
    const float inv2pi = 0.15915494309189535f;
#pragma unroll
    for (int ni = 0; ni < 2; ni++) {
      const int i = (w & 1) * 32 + ni * 16 + l15;   // rope dim, < 64
      const float inv_rev = exp2f(-(float)i * c2) * inv2pi;  // freq in revolutions
#pragma unroll
      for (int mi = 0; mi < 4; mi++) {
#pragma unroll
        for (int r = 0; r < 4; r++) {
          const int t = m0 + mbase + mi * 16 + quad * 4 + r;
          float rev = (float)t * inv_rev;
          rev = rev - floorf(rev);                 // reduce to [0,1) for v_sin/v_cos
          const float sn = __builtin_amdgcn_sinf(rev);   // sin(2*pi*rev)
          const float cs = __builtin_amdgcn_cosf(rev);   // cos(2*pi*rev)
          const float x1 = acc[mi][ni][r], x2 = acc[mi][ni + 2][r];
          unsigned short* p = dst + (size_t)t * stride + hoff + i;
          p[0]  = f2b(x1 * cs - x2 * sn);
          p[64] = f2b(x1 * sn + x2 * cs);
        }
      }
    }
  }
}

// ------------------------------------------------- GEMM C = A * B^T (fp32 out, m97)
__global__ __launch_bounds__(256) void gemm_bt(const unsigned short* __restrict__ A,
                                               const unsigned short* __restrict__ B,
                                               float* __restrict__ Cout,
                                               int M, int N, int K) {
  __shared__ unsigned short As[128 * 32];
  __shared__ unsigned short Bs[128 * 32];
  const int tid = threadIdx.x;
  const int w = tid >> 6, lane = tid & 63;
  const int quad = lane >> 4, l15 = lane & 15;
  const int m0 = blockIdx.x * 128, n0 = blockIdx.y * 128;
  const int mbase = (w >> 1) * 64, nbase = (w & 1) * 64;
  const f32x4 fzero = {0.f, 0.f, 0.f, 0.f};

  f32x4 acc[4][4];
#pragma unroll
  for (int i = 0; i < 4; i++)
#pragma unroll
    for (int j = 0; j < 4; j++) acc[i][j] = fzero;

  const int srow = w * 16 + (lane >> 2);
  const int scol = (lane & 3) * 8;
  const unsigned short* Ag0 = A + (size_t)(m0 + srow) * K + scol;
  const unsigned short* Ag1 = Ag0 + (size_t)64 * K;
  const unsigned short* Bg0 = B + (size_t)(n0 + srow) * K + scol;
  const unsigned short* Bg1 = Bg0 + (size_t)64 * K;

  for (int k0 = 0; k0 < K; k0 += 32) {
    __syncthreads();
    glds16(Ag0 + k0, &As[w * 512]);
    glds16(Ag1 + k0, &As[2048 + w * 512]);
    glds16(Bg0 + k0, &Bs[w * 512]);
    glds16(Bg1 + k0, &Bs[2048 + w * 512]);
    __syncthreads();
    short8 af[4], bf[4];
#pragma unroll
    for (int mi = 0; mi < 4; mi++)
      af[mi] = *(const short8*)&As[(mbase + mi * 16 + l15) * 32 + quad * 8];
#pragma unroll
    for (int ni = 0; ni < 4; ni++)
      bf[ni] = *(const short8*)&Bs[(nbase + ni * 16 + l15) * 32 + quad * 8];
#pragma unroll
    for (int mi = 0; mi < 4; mi++)
#pragma unroll
      for (int ni = 0; ni < 4; ni++)
        acc[mi][ni] = __builtin_amdgcn_mfma_f32_16x16x32_bf16(af[mi], bf[ni], acc[mi][ni], 0, 0, 0);
  }

#pragma unroll
  for (int mi = 0; mi < 4; mi++)
#pragma unroll
    for (int ni = 0; ni < 4; ni++) {
      const int row = m0 + mbase + mi * 16 + quad * 4;
      const int col = n0 + nbase + ni * 16 + l15;
#pragma unroll
      for (int r = 0; r < 4; r++)
        Cout[(size_t)(row + r) * N + col] = acc[mi][ni][r];
    }
}

// ------------------------------------------------------------ windowed GQA attention
// Block: 8 waves, 64 queries, one kv group. wave w: head g*4+(w&3), query-half w>>2.
// All 8 waves share one K/V staging stream.
__global__ __launch_bounds__(512) void attn_fwd(const unsigned short* __restrict__ qp,
                                                const unsigned short* __restrict__ kp,
                                                const unsigned short* __restrict__ vtg,
                                                unsigned short* __restrict__ op) {
  __shared__ unsigned short Ks[2][4][1024];   // [buf][kb][key*32+d']
  __shared__ unsigned short Vt[2][4096];      // [buf][d*32+key]
  const int tid = threadIdx.x;
  const int w = tid >> 6, lane = tid & 63;
  const int quad = lane >> 4, l15 = lane & 15;
  const int t0 = blockIdx.x * 64;
  const int g = blockIdx.y;
  const int h = g * 4 + (w & 3);
  const int t0w = t0 + (w >> 2) * 32;         // this wave's 32-query base
  const f32x4 fzero = {0.f, 0.f, 0.f, 0.f};
  const float scale = 0.088388347648318447f;  // 1/sqrt(128)
  const float NEG_INF = -__builtin_inff();

  short8 qf[4][2];
#pragma unroll
  for (int qt = 0; qt < 2; qt++) {
    const unsigned short* qrow = qp + (size_t)(t0w + qt * 16 + l15) * 2048 + h * 128 + quad * 8;
#pragma unroll
    for (int kb = 0; kb < 4; kb++) qf[kb][qt] = *(const short8*)(qrow + kb * 32);
  }

  f32x4 oacc[8][2];
#pragma unroll
  for (int db = 0; db < 8; db++) { oacc[db][0] = fzero; oacc[db][1] = fzero; }
  float Mrow[2] = {-1.0e30f, -1.0e30f}, Lrow[2] = {0.f, 0.f};

  const int s_begin = (t0 >= 512) ? (t0 - 512) : 0;
  const int nch = ((t0 + 63 - s_begin) >> 5) + 1;

  const int r4 = lane >> 2, c4 = lane & 3;
  // wave w<4 stages K slab w; wave w>=4 stages V^T quarter (w-4). 2 glds16 each.
#define ATTN_STAGE(s0_, b_)                                                              \
  {                                                                                      \
    const int s0v = (s0_);                                                               \
    if (w < 4) {                                                                         \
      _Pragma("unroll")                                                                  \
      for (int p = 0; p < 2; p++)                                                        \
        glds16(kp + (size_t)(s0v + p * 16 + r4) * 512 + g * 128 + w * 32 + c4 * 8,       \
               &Ks[b_][w][p * 512]);                                                     \
    } else {                                                                             \
      const int wv = w - 4;                                                              \
      _Pragma("unroll")                                                                  \
      for (int p = 0; p < 2; p++)                                                        \
        glds16(vtg + (size_t)(g * 128 + wv * 32 + p * 16 + r4) * 4096 + s0v + c4 * 8,    \
               &Vt[b_][wv * 1024 + p * 512]);                                            \
    }                                                                                    \
  }

  ATTN_STAGE(s_begin, 0);

  for (int c = 0; c < nch; ++c) {
    const int s0 = s_begin + c * 32;
    const int b = c & 1;
    __syncthreads();                       // drain glds for chunk c (uniform)
    if (c + 1 < nch) ATTN_STAGE(s_begin + (c + 1) * 32, (c + 1) & 1);

    // wave-relevance: this wave's queries [t0w, t0w+31] vs keys [s0, s0+31]
    if (s0 + 31 >= t0w - 512 && s0 <= t0w + 31) {
      // ---- S^T = K * Q^T, permuted key rows
      f32x4 sacc[2][2];
      sacc[0][0] = fzero; sacc[0][1] = fzero; sacc[1][0] = fzero; sacc[1][1] = fzero;
      const int permBase = ((l15 >> 2) << 3) + (l15 & 3);   // + 4*kt
#pragma unroll
      for (int kb = 0; kb < 4; kb++) {
        short8 af0 = *(const short8*)&Ks[b][kb][(permBase + 0) * 32 + quad * 8];
        short8 af1 = *(const short8*)&Ks[b][kb][(permBase + 4) * 32 + quad * 8];
        sacc[0][0] = __builtin_amdgcn_mfma_f32_16x16x32_bf16(af0, qf[kb][0], sacc[0][0], 0, 0, 0);
        sacc[0][1] = __builtin_amdgcn_mfma_f32_16x16x32_bf16(af0, qf[kb][1], sacc[0][1], 0, 0, 0);
        sacc[1][0] = __builtin_amdgcn_mfma_f32_16x16x32_bf16(af1, qf[kb][0], sacc[1][0], 0, 0, 0);
        sacc[1][1] = __builtin_amdgcn_mfma_f32_16x16x32_bf16(af1, qf[kb][1], sacc[1][1], 0, 0, 0);
      }

      // ---- masked online softmax; key for (kt,r) = s0 + quad*8 + kt*4 + r
      short8 pb[2];
      float alpha[2];
#pragma unroll
      for (int qt = 0; qt < 2; qt++) {
        const int tq = t0w + qt * 16 + l15;
        float vals[8];
        float cmax = NEG_INF;
#pragma unroll
        for (int kt = 0; kt < 2; kt++)
#pragma unroll
          for (int r = 0; r < 4; r++) {
            const int s = s0 + quad * 8 + kt * 4 + r;
            const bool ok = (unsigned)(tq - s) <= 512u;
            const float v = ok ? sacc[kt][qt][r] * scale : NEG_INF;
            vals[kt * 4 + r] = v;
            cmax = fmaxf(cmax, v);
          }
        cmax = fmaxf(cmax, __shfl_xor(cmax, 16));
        cmax = fmaxf(cmax, __shfl_xor(cmax, 32));
        const float Mnew = fmaxf(Mrow[qt], cmax);
        alpha[qt] = __expf(Mrow[qt] - Mnew);
        Mrow[qt] = Mnew;
        float csum = 0.f;
#pragma unroll
        for (int j = 0; j < 8; j++) {
          const float p = __expf(vals[j] - Mnew);   // exp(-inf) = 0 for masked
          csum += p;
          pb[qt][j] = (short)f2b(p);
        }
        csum += __shfl_xor(csum, 16);
        csum += __shfl_xor(csum, 32);
        Lrow[qt] = Lrow[qt] * alpha[qt] + csum;
      }

      // ---- O^T += V^T * P^T
#pragma unroll
      for (int db = 0; db < 8; db++) {
        short8 vf = *(const short8*)&Vt[b][(db * 16 + l15) * 32 + quad * 8];
#pragma unroll
        for (int qt = 0; qt < 2; qt++) {
          oacc[db][qt][0] *= alpha[qt]; oacc[db][qt][1] *= alpha[qt];
          oacc[db][qt][2] *= alpha[qt]; oacc[db][qt][3] *= alpha[qt];
          oacc[db][qt] = __builtin_amdgcn_mfma_f32_16x16x32_bf16(vf, pb[qt], oacc[db][qt], 0, 0, 0);
        }
      }
    }
  }
#undef ATTN_STAGE

#pragma unroll
  for (int qt = 0; qt < 2; qt++) {
    const float invL = 1.f / Lrow[qt];
    unsigned short* orow = op + (size_t)(t0w + qt * 16 + l15) * 2048 + h * 128;
#pragma unroll
    for (int db = 0; db < 8; db++) {
      u16x4 o;
#pragma unroll
      for (int r = 0; r < 4; r++) o[r] = f2b(oacc[db][qt][r] * invL);
      *(u16x4*)(orow + db * 16 + quad * 4) = o;
    }
  }
}

// ---------------------------------------------------------------- launch
extern "C" void kernel_launch(void* const* d_in, const int* in_sizes, int n_in,
                              void* d_out, int out_size, void* d_ws, size_t ws_size,
                              hipStream_t stream) {
  const float* x  = (const float*)d_in[0];
  const float* wq = (const float*)d_in[1];
  const float* wk = (const float*)d_in[2];
  const float* wv = (const float*)d_in[3];
  const float* wo = (const float*)d_in[4];
  float* out = (float*)d_out;
  char* ws = (char*)d_ws;

  // workspace map (~63 MB); attnb aliases xb (dead after gemm_qkv)
  unsigned short* xb    = (unsigned short*)(ws + 0);           // 16,777,216 B
  unsigned short* wqkv  = (unsigned short*)(ws + 16777216);    // 12,582,912 B
  unsigned short* wob   = (unsigned short*)(ws + 29360128);    //  8,388,608 B
  unsigned short* qb    = (unsigned short*)(ws + 37748736);    // 16,777,216 B
  unsigned short* kbuf  = (unsigned short*)(ws + 54525952);    //  4,194,304 B
  unsigned short* vtg   = (unsigned short*)(ws + 58720256);    //  4,194,304 B
  unsigned short* attnb = xb;

  cast_all<<<18432, 256, 0, stream>>>(x, wq, wk, wv, wo, (unsigned short*)ws);

  // qkv proj + fused RoPE + fused V-transpose
  gemm_qkv<<<dim3(32, 24), 256, 0, stream>>>(xb, wqkv, qb, kbuf, vtg);

  attn_fwd<<<dim3(64, 4), 512, 0, stream>>>(qb, kbuf, vtg, attnb);

  // out = attn @ wo^T  (4096 x 2048, K=2048), fp32 out
  gemm_bt<<<dim3(32, 16), 256, 0, stream>>>(attnb, wob, out, 4096, 2048, 2048);
}